// Round 1
// baseline (3636.101 us; speedup 1.0000x reference)
//
#include <hip/hip_runtime.h>

typedef unsigned short u16;
typedef float f32x4 __attribute__((ext_vector_type(4)));
typedef short s16x8 __attribute__((ext_vector_type(8)));

#define T_TOK   16448L   // 257*64
#define D_DIM   768L
#define H_DIM   3072L
#define E_NUM   8L
#define M_PAD   16512L   // 129*128

// ---------- helpers ----------
__device__ __forceinline__ u16 f2bf(float f){
  unsigned u = __float_as_uint(f);
  u = u + 0x7FFFu + ((u >> 16) & 1u);          // RNE
  return (u16)(u >> 16);
}
__device__ __forceinline__ unsigned f2bf2(float a, float b){
  return (unsigned)f2bf(a) | ((unsigned)f2bf(b) << 16);
}

__device__ __forceinline__ void gload_lds16(const u16* g, u16* s){
  __builtin_amdgcn_global_load_lds((const __attribute__((address_space(1))) void*)g,
                                   (__attribute__((address_space(3))) void*)s,
                                   16, 0, 0);
}

// ---------- fp32 -> bf16 (optionally zero-padded tail) ----------
__global__ void k_conv(const float* __restrict__ in, u16* __restrict__ outp,
                       long nValid, long nTotal){
  long i = (long)blockIdx.x * blockDim.x + threadIdx.x;
  long stride = (long)gridDim.x * blockDim.x;
  long n8 = nTotal >> 3;
  for (long v = i; v < n8; v += stride){
    long base = v << 3;
    uint4 o;
    if (base < nValid){
      const float4 f0 = *(const float4*)(in + base);
      const float4 f1 = *(const float4*)(in + base + 4);
      o.x = f2bf2(f0.x, f0.y); o.y = f2bf2(f0.z, f0.w);
      o.z = f2bf2(f1.x, f1.y); o.w = f2bf2(f1.z, f1.w);
    } else {
      o.x = 0u; o.y = 0u; o.z = 0u; o.w = 0u;
    }
    *(uint4*)(outp + base) = o;
  }
}

// ---------- router: logits + softmax (fp32, one wave per token) ----------
__global__ void k_router(const float* __restrict__ x, const float* __restrict__ Wr,
                         const float* __restrict__ br, float* __restrict__ probs){
  int w = (int)((blockIdx.x * (long)blockDim.x + threadIdx.x) >> 6);
  int lane = threadIdx.x & 63;
  if (w >= (int)T_TOK) return;
  const float* xr = x + (long)w * D_DIM;
  float l[8];
#pragma unroll
  for (int e = 0; e < 8; ++e) l[e] = 0.f;
#pragma unroll
  for (int c = 0; c < 3; ++c){
    const float4 xv = *(const float4*)(xr + c*256 + lane*4);
#pragma unroll
    for (int e = 0; e < 8; ++e){
      const float4 wv = *(const float4*)(Wr + (long)e*D_DIM + c*256 + lane*4);
      l[e] += xv.x*wv.x + xv.y*wv.y + xv.z*wv.z + xv.w*wv.w;
    }
  }
#pragma unroll
  for (int e = 0; e < 8; ++e){
#pragma unroll
    for (int off = 32; off > 0; off >>= 1) l[e] += __shfl_xor(l[e], off);
    l[e] += br[e];
  }
  float m = l[0];
#pragma unroll
  for (int e = 1; e < 8; ++e) m = fmaxf(m, l[e]);
  float s = 0.f;
#pragma unroll
  for (int e = 0; e < 8; ++e){ l[e] = __expf(l[e] - m); s += l[e]; }
  float inv = 1.f / s;
  if (lane == 0){
    float4 p0 = { l[0]*inv, l[1]*inv, l[2]*inv, l[3]*inv };
    float4 p1 = { l[4]*inv, l[5]*inv, l[6]*inv, l[7]*inv };
    *(float4*)(probs + (long)w*8)     = p0;
    *(float4*)(probs + (long)w*8 + 4) = p1;
  }
}

// ---------- GEMM building blocks (m97 structure, 128x128 tile, BK=64) ----------
// LDS tile [128 rows][64 cols] bf16, linear, global_load_lds width-16.
// Bank-conflict fix: XOR-swizzle the 16B column-block by (row&7) — applied on the
// global SOURCE address at stage time (LDS dest must stay linear, m104/m173) and
// reproduced on the ds_read side.
__device__ __forceinline__ void stage_tile(const u16* __restrict__ gbase, int ldk,
                                           u16* sbase, int wave, int lane){
  const int rw = lane >> 3;                    // 0..7 row-in-group
  const int c8 = (lane & 7) ^ rw;              // swizzled source 16B-block
  const u16* g = gbase + (long)(wave*8 + rw) * ldk + c8*8;
  u16* s = sbase + wave*512;                   // wave-uniform LDS base (elements)
#pragma unroll
  for (int i = 0; i < 4; ++i){
    gload_lds16(g + (long)i*32*ldk, s + i*2048);   // rows i*32 + wave*8 + rw
  }
}

__device__ __forceinline__ void mma_step(const u16* As, const u16* Bs, int lane,
                                         int wr, int wc, f32x4 (&acc)[4][4]){
  const int g  = lane >> 4;
  const int ln = lane & 15;
  const int rA = wr*64 + ln;
  const int rB = wc*64 + ln;
#pragma unroll
  for (int kk = 0; kk < 2; ++kk){
    const int co = (((kk<<2) | g) ^ (ln & 7)) << 3;   // swizzled col offset (elems)
    s16x8 a[4], b[4];
#pragma unroll
    for (int mi = 0; mi < 4; ++mi) a[mi] = *(const s16x8*)(As + (rA + mi*16)*64 + co);
#pragma unroll
    for (int ni = 0; ni < 4; ++ni) b[ni] = *(const s16x8*)(Bs + (rB + ni*16)*64 + co);
#pragma unroll
    for (int mi = 0; mi < 4; ++mi)
#pragma unroll
      for (int ni = 0; ni < 4; ++ni)
        acc[mi][ni] = __builtin_amdgcn_mfma_f32_16x16x32_bf16(a[mi], b[ni], acc[mi][ni], 0, 0, 0);
  }
}

// ---------- GEMM1: h = quick_gelu(x @ W1[e]^T + b1[e])  (per expert, z = e) ----------
__global__ __launch_bounds__(256) void k_gemm1(const u16* __restrict__ xb,
                                               const u16* __restrict__ w1b,
                                               const float* __restrict__ b1,
                                               u16* __restrict__ hb,
                                               int t0, int mcAlloc){
  __shared__ alignas(16) u16 As[8192];
  __shared__ alignas(16) u16 Bs[8192];
  const int e  = blockIdx.z;
  const int m0 = blockIdx.x << 7;
  const int n0 = blockIdx.y << 7;
  const int tid = threadIdx.x, lane = tid & 63, wave = tid >> 6;
  const int wr = wave >> 1, wc = wave & 1;
  f32x4 acc[4][4] = {};
  const u16* Ab = xb  + (long)(t0 + m0) * D_DIM;
  const u16* Bb = w1b + ((long)e * H_DIM + n0) * D_DIM;
  for (int kt = 0; kt < 12; ++kt){
    stage_tile(Ab + kt*64, (int)D_DIM, As, wave, lane);
    stage_tile(Bb + kt*64, (int)D_DIM, Bs, wave, lane);
    __syncthreads();
    mma_step(As, Bs, lane, wr, wc, acc);
    __syncthreads();
  }
  const int ln = lane & 15;
  float bias[4];
#pragma unroll
  for (int ni = 0; ni < 4; ++ni) bias[ni] = b1[(long)e*H_DIM + n0 + wc*64 + ni*16 + ln];
  u16* hE = hb + (long)e * mcAlloc * H_DIM;
#pragma unroll
  for (int mi = 0; mi < 4; ++mi){
#pragma unroll
    for (int j = 0; j < 4; ++j){
      const int r = m0 + wr*64 + mi*16 + (lane>>4)*4 + j;   // chunk-local row
      u16* dst = hE + (long)r * H_DIM + n0 + wc*64;
#pragma unroll
      for (int ni = 0; ni < 4; ++ni){
        const float v  = acc[mi][ni][j] + bias[ni];
        const float gl = v / (1.0f + __expf(-1.702f * v));  // quick_gelu
        dst[ni*16 + ln] = f2bf(gl);
      }
    }
  }
}

// ---------- GEMM2: y = sum_e probs[:,e] * (h_e @ W2[e]^T + b2[e]) ----------
__global__ __launch_bounds__(256) void k_gemm2(const u16* __restrict__ hb,
                                               const u16* __restrict__ w2b,
                                               const float* __restrict__ b2,
                                               const float* __restrict__ probs,
                                               float* __restrict__ out,
                                               int t0, int mcAlloc){
  __shared__ alignas(16) u16 As[8192];
  __shared__ alignas(16) u16 Bs[8192];
  const int m0 = blockIdx.x << 7;
  const int n0 = blockIdx.y << 7;
  const int tid = threadIdx.x, lane = tid & 63, wave = tid >> 6;
  const int wr = wave >> 1, wc = wave & 1;
  const int ln = lane & 15;
  f32x4 y[4][4] = {};
  for (int e = 0; e < 8; ++e){
    f32x4 acc[4][4] = {};
    const u16* Ab = hb  + ((long)e * mcAlloc + m0) * H_DIM;
    const u16* Bb = w2b + ((long)e * D_DIM  + n0) * H_DIM;
    for (int kt = 0; kt < 48; ++kt){
      stage_tile(Ab + kt*64, (int)H_DIM, As, wave, lane);
      stage_tile(Bb + kt*64, (int)H_DIM, Bs, wave, lane);
      __syncthreads();
      mma_step(As, Bs, lane, wr, wc, acc);
      __syncthreads();
    }
    float bias[4];
#pragma unroll
    for (int ni = 0; ni < 4; ++ni) bias[ni] = b2[(long)e*D_DIM + n0 + wc*64 + ni*16 + ln];
#pragma unroll
    for (int mi = 0; mi < 4; ++mi){
#pragma unroll
      for (int j = 0; j < 4; ++j){
        const int gt = t0 + m0 + wr*64 + mi*16 + (lane>>4)*4 + j;
        const float p = (gt < (int)T_TOK) ? probs[(long)gt*8 + e] : 0.f;
#pragma unroll
        for (int ni = 0; ni < 4; ++ni)
          y[mi][ni][j] += p * (acc[mi][ni][j] + bias[ni]);
      }
    }
  }
#pragma unroll
  for (int mi = 0; mi < 4; ++mi){
#pragma unroll
    for (int j = 0; j < 4; ++j){
      const int gt = t0 + m0 + wr*64 + mi*16 + (lane>>4)*4 + j;
      if (gt < (int)T_TOK){
        float* dst = out + (long)gt * D_DIM + n0 + wc*64;
#pragma unroll
        for (int ni = 0; ni < 4; ++ni) dst[ni*16 + ln] = y[mi][ni][j];
      }
    }
  }
}

// ---------- host ----------
extern "C" void kernel_launch(void* const* d_in, const int* in_sizes, int n_in,
                              void* d_out, int out_size, void* d_ws, size_t ws_size,
                              hipStream_t stream){
  const float* x  = (const float*)d_in[0];
  const float* W1 = (const float*)d_in[1];
  const float* b1 = (const float*)d_in[2];
  const float* W2 = (const float*)d_in[3];
  const float* b2 = (const float*)d_in[4];
  const float* Wr = (const float*)d_in[5];
  const float* br = (const float*)d_in[6];
  float* out = (float*)d_out;

  char* ws = (char*)d_ws;
  size_t off = 0;
  auto carve = [&](size_t bytes)->void*{
    void* p = ws + off; off += (bytes + 255) & ~(size_t)255; return p;
  };
  u16*   xb    = (u16*)  carve((size_t)M_PAD * D_DIM * 2);
  u16*   w1b   = (u16*)  carve((size_t)E_NUM * H_DIM * D_DIM * 2);
  u16*   w2b   = (u16*)  carve((size_t)E_NUM * D_DIM * H_DIM * 2);
  float* probs = (float*)carve((size_t)T_TOK * E_NUM * 4);

  size_t remain = (ws_size > off) ? (ws_size - off) : 0;
  long mcAlloc = (long)(remain / ((size_t)E_NUM * H_DIM * 2));
  mcAlloc = (mcAlloc / 128) * 128;
  if (mcAlloc > M_PAD) mcAlloc = M_PAD;
  if (mcAlloc < 128)   mcAlloc = 128;   // last-resort; needs ~108 MB ws minimum
  u16* hb = (u16*)carve((size_t)E_NUM * mcAlloc * H_DIM * 2);

  // conversions + router (independent of chunking)
  k_conv<<<dim3(2048), dim3(256), 0, stream>>>(x,  xb,  T_TOK*D_DIM, M_PAD*D_DIM);
  k_conv<<<dim3(2048), dim3(256), 0, stream>>>(W1, w1b, E_NUM*H_DIM*D_DIM, E_NUM*H_DIM*D_DIM);
  k_conv<<<dim3(2048), dim3(256), 0, stream>>>(W2, w2b, E_NUM*D_DIM*H_DIM, E_NUM*D_DIM*H_DIM);
  k_router<<<dim3(4112), dim3(256), 0, stream>>>(x, Wr, br, probs);

  for (long t0 = 0; t0 < M_PAD; t0 += mcAlloc){
    long mcur = M_PAD - t0; if (mcur > mcAlloc) mcur = mcAlloc;
    dim3 g1((unsigned)(mcur/128), 24, 8);
    k_gemm1<<<g1, dim3(256), 0, stream>>>(xb, w1b, b1, hb, (int)t0, (int)mcAlloc);
    dim3 g2((unsigned)(mcur/128), 6, 1);
    k_gemm2<<<g2, dim3(256), 0, stream>>>(hb, w2b, b2, probs, out, (int)t0, (int)mcAlloc);
  }
}

// Round 2
// 2719.188 us; speedup vs baseline: 1.3372x; 1.3372x over previous
//
#include <hip/hip_runtime.h>

typedef unsigned short u16;
typedef float f32x4 __attribute__((ext_vector_type(4)));
typedef short s16x8 __attribute__((ext_vector_type(8)));

#define T_TOK   16448L   // 257*64
#define D_DIM   768L
#define H_DIM   3072L
#define E_NUM   8L
#define M_PAD   16512L   // 129*128

// ---------- helpers ----------
__device__ __forceinline__ u16 f2bf(float f){
  unsigned u = __float_as_uint(f);
  u = u + 0x7FFFu + ((u >> 16) & 1u);          // RNE
  return (u16)(u >> 16);
}
__device__ __forceinline__ unsigned f2bf2(float a, float b){
  return (unsigned)f2bf(a) | ((unsigned)f2bf(b) << 16);
}

__device__ __forceinline__ void gload_lds16(const u16* g, u16* s){
  __builtin_amdgcn_global_load_lds((const __attribute__((address_space(1))) void*)g,
                                   (__attribute__((address_space(3))) void*)s,
                                   16, 0, 0);
}

// ---------- fp32 -> bf16 (optionally zero-padded tail) ----------
__global__ void k_conv(const float* __restrict__ in, u16* __restrict__ outp,
                       long nValid, long nTotal){
  long i = (long)blockIdx.x * blockDim.x + threadIdx.x;
  long stride = (long)gridDim.x * blockDim.x;
  long n8 = nTotal >> 3;
  for (long v = i; v < n8; v += stride){
    long base = v << 3;
    uint4 o;
    if (base < nValid){
      const float4 f0 = *(const float4*)(in + base);
      const float4 f1 = *(const float4*)(in + base + 4);
      o.x = f2bf2(f0.x, f0.y); o.y = f2bf2(f0.z, f0.w);
      o.z = f2bf2(f1.x, f1.y); o.w = f2bf2(f1.z, f1.w);
    } else {
      o.x = 0u; o.y = 0u; o.z = 0u; o.w = 0u;
    }
    *(uint4*)(outp + base) = o;
  }
}

// ---------- router: logits + softmax (fp32, one wave per token) ----------
__global__ void k_router(const float* __restrict__ x, const float* __restrict__ Wr,
                         const float* __restrict__ br, float* __restrict__ probs){
  int w = (int)((blockIdx.x * (long)blockDim.x + threadIdx.x) >> 6);
  int lane = threadIdx.x & 63;
  if (w >= (int)T_TOK) return;
  const float* xr = x + (long)w * D_DIM;
  float l[8];
#pragma unroll
  for (int e = 0; e < 8; ++e) l[e] = 0.f;
#pragma unroll
  for (int c = 0; c < 3; ++c){
    const float4 xv = *(const float4*)(xr + c*256 + lane*4);
#pragma unroll
    for (int e = 0; e < 8; ++e){
      const float4 wv = *(const float4*)(Wr + (long)e*D_DIM + c*256 + lane*4);
      l[e] += xv.x*wv.x + xv.y*wv.y + xv.z*wv.z + xv.w*wv.w;
    }
  }
#pragma unroll
  for (int e = 0; e < 8; ++e){
#pragma unroll
    for (int off = 32; off > 0; off >>= 1) l[e] += __shfl_xor(l[e], off);
    l[e] += br[e];
  }
  float m = l[0];
#pragma unroll
  for (int e = 1; e < 8; ++e) m = fmaxf(m, l[e]);
  float s = 0.f;
#pragma unroll
  for (int e = 0; e < 8; ++e){ l[e] = __expf(l[e] - m); s += l[e]; }
  float inv = 1.f / s;
  if (lane == 0){
    float4 p0 = { l[0]*inv, l[1]*inv, l[2]*inv, l[3]*inv };
    float4 p1 = { l[4]*inv, l[5]*inv, l[6]*inv, l[7]*inv };
    *(float4*)(probs + (long)w*8)     = p0;
    *(float4*)(probs + (long)w*8 + 4) = p1;
  }
}

// ---------- GEMM building blocks (m97 structure, 128x128 tile, BK=64) ----------
__device__ __forceinline__ void stage_tile(const u16* __restrict__ gbase, int ldk,
                                           u16* sbase, int wave, int lane){
  const int rw = lane >> 3;                    // 0..7 row-in-group
  const int c8 = (lane & 7) ^ rw;              // swizzled source 16B-block
  const u16* g = gbase + (long)(wave*8 + rw) * ldk + c8*8;
  u16* s = sbase + wave*512;                   // wave-uniform LDS base (elements)
#pragma unroll
  for (int i = 0; i < 4; ++i){
    gload_lds16(g + (long)i*32*ldk, s + i*2048);   // rows i*32 + wave*8 + rw
  }
}

__device__ __forceinline__ void mma_step(const u16* As, const u16* Bs, int lane,
                                         int wr, int wc, f32x4 (&acc)[4][4]){
  const int g  = lane >> 4;
  const int ln = lane & 15;
  const int rA = wr*64 + ln;
  const int rB = wc*64 + ln;
#pragma unroll
  for (int kk = 0; kk < 2; ++kk){
    const int co = (((kk<<2) | g) ^ (ln & 7)) << 3;   // swizzled col offset (elems)
    s16x8 a[4], b[4];
#pragma unroll
    for (int mi = 0; mi < 4; ++mi) a[mi] = *(const s16x8*)(As + (rA + mi*16)*64 + co);
#pragma unroll
    for (int ni = 0; ni < 4; ++ni) b[ni] = *(const s16x8*)(Bs + (rB + ni*16)*64 + co);
#pragma unroll
    for (int mi = 0; mi < 4; ++mi)
#pragma unroll
      for (int ni = 0; ni < 4; ++ni)
        acc[mi][ni] = __builtin_amdgcn_mfma_f32_16x16x32_bf16(a[mi], b[ni], acc[mi][ni], 0, 0, 0);
  }
}

// ---------- GEMM1: hb = quick_gelu(x @ W1[e]^T + b1[e])   (single expert e) ----------
__global__ __launch_bounds__(256) void k_gemm1(const u16* __restrict__ xb,
                                               const u16* __restrict__ w1b,
                                               const float* __restrict__ b1,
                                               u16* __restrict__ hb,
                                               int e){
  __shared__ alignas(16) u16 As[8192];
  __shared__ alignas(16) u16 Bs[8192];
  const int m0 = blockIdx.x << 7;
  const int n0 = blockIdx.y << 7;
  const int tid = threadIdx.x, lane = tid & 63, wave = tid >> 6;
  const int wr = wave >> 1, wc = wave & 1;
  f32x4 acc[4][4] = {};
  const u16* Ab = xb  + (long)m0 * D_DIM;
  const u16* Bb = w1b + ((long)e * H_DIM + n0) * D_DIM;
  for (int kt = 0; kt < 12; ++kt){
    stage_tile(Ab + kt*64, (int)D_DIM, As, wave, lane);
    stage_tile(Bb + kt*64, (int)D_DIM, Bs, wave, lane);
    __syncthreads();
    mma_step(As, Bs, lane, wr, wc, acc);
    __syncthreads();
  }
  const int ln = lane & 15;
  float bias[4];
#pragma unroll
  for (int ni = 0; ni < 4; ++ni) bias[ni] = b1[(long)e*H_DIM + n0 + wc*64 + ni*16 + ln];
#pragma unroll
  for (int mi = 0; mi < 4; ++mi){
#pragma unroll
    for (int j = 0; j < 4; ++j){
      const int r = m0 + wr*64 + mi*16 + (lane>>4)*4 + j;
      u16* dst = hb + (long)r * H_DIM + n0 + wc*64;
#pragma unroll
      for (int ni = 0; ni < 4; ++ni){
        const float v  = acc[mi][ni][j] + bias[ni];
        const float gl = v / (1.0f + __expf(-1.702f * v));  // quick_gelu
        dst[ni*16 + ln] = f2bf(gl);
      }
    }
  }
}

// ---------- GEMM2: out (+)= probs[:,e] * (hb @ W2[e]^T + b2[e]) ----------
__global__ __launch_bounds__(256) void k_gemm2(const u16* __restrict__ hb,
                                               const u16* __restrict__ w2b,
                                               const float* __restrict__ b2,
                                               const float* __restrict__ probs,
                                               float* __restrict__ out,
                                               int e){
  __shared__ alignas(16) u16 As[8192];
  __shared__ alignas(16) u16 Bs[8192];
  const int m0 = blockIdx.x << 7;
  const int n0 = blockIdx.y << 7;
  const int tid = threadIdx.x, lane = tid & 63, wave = tid >> 6;
  const int wr = wave >> 1, wc = wave & 1;
  const int ln = lane & 15;
  f32x4 acc[4][4] = {};
  const u16* Ab = hb  + (long)m0 * H_DIM;
  const u16* Bb = w2b + ((long)e * D_DIM + n0) * H_DIM;
  for (int kt = 0; kt < 48; ++kt){
    stage_tile(Ab + kt*64, (int)H_DIM, As, wave, lane);
    stage_tile(Bb + kt*64, (int)H_DIM, Bs, wave, lane);
    __syncthreads();
    mma_step(As, Bs, lane, wr, wc, acc);
    __syncthreads();
  }
  float bias[4];
#pragma unroll
  for (int ni = 0; ni < 4; ++ni) bias[ni] = b2[(long)e*D_DIM + n0 + wc*64 + ni*16 + ln];
#pragma unroll
  for (int mi = 0; mi < 4; ++mi){
#pragma unroll
    for (int j = 0; j < 4; ++j){
      const int gt = m0 + wr*64 + mi*16 + (lane>>4)*4 + j;
      if (gt < (int)T_TOK){
        const float p = probs[(long)gt*8 + e];
        float* dst = out + (long)gt * D_DIM + n0 + wc*64;
#pragma unroll
        for (int ni = 0; ni < 4; ++ni){
          const float v = p * (acc[mi][ni][j] + bias[ni]);
          if (e == 0) dst[ni*16 + ln] = v;
          else        dst[ni*16 + ln] += v;
        }
      }
    }
  }
}

// ---------- host ----------
extern "C" void kernel_launch(void* const* d_in, const int* in_sizes, int n_in,
                              void* d_out, int out_size, void* d_ws, size_t ws_size,
                              hipStream_t stream){
  const float* x  = (const float*)d_in[0];
  const float* W1 = (const float*)d_in[1];
  const float* b1 = (const float*)d_in[2];
  const float* W2 = (const float*)d_in[3];
  const float* b2 = (const float*)d_in[4];
  const float* Wr = (const float*)d_in[5];
  const float* br = (const float*)d_in[6];
  float* out = (float*)d_out;

  char* ws = (char*)d_ws;
  size_t off = 0;
  auto carve = [&](size_t bytes)->void*{
    void* p = ws + off; off += (bytes + 255) & ~(size_t)255; return p;
  };
  u16*   xb    = (u16*)  carve((size_t)M_PAD * D_DIM * 2);
  u16*   w1b   = (u16*)  carve((size_t)E_NUM * H_DIM * D_DIM * 2);
  u16*   w2b   = (u16*)  carve((size_t)E_NUM * D_DIM * H_DIM * 2);
  float* probs = (float*)carve((size_t)T_TOK * E_NUM * 4);
  u16*   hb    = (u16*)  carve((size_t)M_PAD * H_DIM * 2);   // ONE expert's h

  // conversions + router
  k_conv<<<dim3(2048), dim3(256), 0, stream>>>(x,  xb,  T_TOK*D_DIM, M_PAD*D_DIM);
  k_conv<<<dim3(2048), dim3(256), 0, stream>>>(W1, w1b, E_NUM*H_DIM*D_DIM, E_NUM*H_DIM*D_DIM);
  k_conv<<<dim3(2048), dim3(256), 0, stream>>>(W2, w2b, E_NUM*D_DIM*H_DIM, E_NUM*D_DIM*H_DIM);
  k_router<<<dim3(4112), dim3(256), 0, stream>>>(x, Wr, br, probs);

  // per-expert GEMM pairs, full-width grids (no chunking)
  for (int e = 0; e < (int)E_NUM; ++e){
    k_gemm1<<<dim3(129, 24), dim3(256), 0, stream>>>(xb, w1b, b1, hb, e);
    k_gemm2<<<dim3(129, 6),  dim3(256), 0, stream>>>(hb, w2b, b2, probs, out, e);
  }
}

// Round 3
// 2235.885 us; speedup vs baseline: 1.6262x; 1.2162x over previous
//
#include <hip/hip_runtime.h>

typedef unsigned short u16;
typedef float f32x4 __attribute__((ext_vector_type(4)));
typedef short s16x8 __attribute__((ext_vector_type(8)));

#define T_TOK   16448L   // 257*64
#define D_DIM   768L
#define H_DIM   3072L
#define E_NUM   8L
#define M_PAD   16512L   // 129*128 ; halves: A=8192 rows (64 tiles), B=8320 rows (65 tiles)

// ---------- helpers ----------
__device__ __forceinline__ u16 f2bf(float f){
  unsigned u = __float_as_uint(f);
  u = u + 0x7FFFu + ((u >> 16) & 1u);          // RNE
  return (u16)(u >> 16);
}
__device__ __forceinline__ unsigned f2bf2(float a, float b){
  return (unsigned)f2bf(a) | ((unsigned)f2bf(b) << 16);
}

__device__ __forceinline__ void gload_lds16(const u16* g, u16* s){
  __builtin_amdgcn_global_load_lds((const __attribute__((address_space(1))) void*)g,
                                   (__attribute__((address_space(3))) void*)s,
                                   16, 0, 0);
}

// bijective XCD chunking (m204): consecutive dispatch ids (round-robin over 8 XCDs)
// -> contiguous logical ranges per XCD
__device__ __forceinline__ int xcd_chunk(int idx, int n){
  const int q = n >> 3, r = n & 7, x = idx & 7;
  return (x < r ? x*(q+1) : r*(q+1) + (x-r)*q) + (idx >> 3);
}

// ---------- fp32 -> bf16 (zero-padded tail) ----------
__global__ void k_conv(const float* __restrict__ in, u16* __restrict__ outp,
                       long nValid, long nTotal){
  long i = (long)blockIdx.x * blockDim.x + threadIdx.x;
  long stride = (long)gridDim.x * blockDim.x;
  long n8 = nTotal >> 3;
  for (long v = i; v < n8; v += stride){
    long base = v << 3;
    uint4 o;
    if (base < nValid){
      const float4 f0 = *(const float4*)(in + base);
      const float4 f1 = *(const float4*)(in + base + 4);
      o.x = f2bf2(f0.x, f0.y); o.y = f2bf2(f0.z, f0.w);
      o.z = f2bf2(f1.x, f1.y); o.w = f2bf2(f1.z, f1.w);
    } else {
      o.x = 0u; o.y = 0u; o.z = 0u; o.w = 0u;
    }
    *(uint4*)(outp + base) = o;
  }
}

// ---------- router: logits + softmax (fp32, one wave per token) ----------
__global__ void k_router(const float* __restrict__ x, const float* __restrict__ Wr,
                         const float* __restrict__ br, float* __restrict__ probs){
  int w = (int)((blockIdx.x * (long)blockDim.x + threadIdx.x) >> 6);
  int lane = threadIdx.x & 63;
  if (w >= (int)T_TOK) return;
  const float* xr = x + (long)w * D_DIM;
  float l[8];
#pragma unroll
  for (int e = 0; e < 8; ++e) l[e] = 0.f;
#pragma unroll
  for (int c = 0; c < 3; ++c){
    const float4 xv = *(const float4*)(xr + c*256 + lane*4);
#pragma unroll
    for (int e = 0; e < 8; ++e){
      const float4 wv = *(const float4*)(Wr + (long)e*D_DIM + c*256 + lane*4);
      l[e] += xv.x*wv.x + xv.y*wv.y + xv.z*wv.z + xv.w*wv.w;
    }
  }
#pragma unroll
  for (int e = 0; e < 8; ++e){
#pragma unroll
    for (int off = 32; off > 0; off >>= 1) l[e] += __shfl_xor(l[e], off);
    l[e] += br[e];
  }
  float m = l[0];
#pragma unroll
  for (int e = 1; e < 8; ++e) m = fmaxf(m, l[e]);
  float s = 0.f;
#pragma unroll
  for (int e = 0; e < 8; ++e){ l[e] = __expf(l[e] - m); s += l[e]; }
  float inv = 1.f / s;
  if (lane == 0){
    float4 p0 = { l[0]*inv, l[1]*inv, l[2]*inv, l[3]*inv };
    float4 p1 = { l[4]*inv, l[5]*inv, l[6]*inv, l[7]*inv };
    *(float4*)(probs + (long)w*8)     = p0;
    *(float4*)(probs + (long)w*8 + 4) = p1;
  }
}

// ---------- GEMM building blocks (m97 structure, 128x128 tile, BK=64) ----------
__device__ __forceinline__ void stage_tile(const u16* __restrict__ gbase, int ldk,
                                           u16* sbase, int wave, int lane){
  const int rw = lane >> 3;                    // 0..7 row-in-group
  const int c8 = (lane & 7) ^ rw;              // swizzled source 16B-block
  const u16* g = gbase + (long)(wave*8 + rw) * ldk + c8*8;
  u16* s = sbase + wave*512;                   // wave-uniform LDS base (elements)
#pragma unroll
  for (int i = 0; i < 4; ++i){
    gload_lds16(g + (long)i*32*ldk, s + i*2048);   // rows i*32 + wave*8 + rw
  }
}

__device__ __forceinline__ void mma_step(const u16* As, const u16* Bs, int lane,
                                         int wr, int wc, f32x4 (&acc)[4][4]){
  const int g  = lane >> 4;
  const int ln = lane & 15;
  const int rA = wr*64 + ln;
  const int rB = wc*64 + ln;
#pragma unroll
  for (int kk = 0; kk < 2; ++kk){
    const int co = (((kk<<2) | g) ^ (ln & 7)) << 3;   // swizzled col offset (elems)
    s16x8 a[4], b[4];
#pragma unroll
    for (int mi = 0; mi < 4; ++mi) a[mi] = *(const s16x8*)(As + (rA + mi*16)*64 + co);
#pragma unroll
    for (int ni = 0; ni < 4; ++ni) b[ni] = *(const s16x8*)(Bs + (rB + ni*16)*64 + co);
#pragma unroll
    for (int mi = 0; mi < 4; ++mi)
#pragma unroll
      for (int ni = 0; ni < 4; ++ni)
        acc[mi][ni] = __builtin_amdgcn_mfma_f32_16x16x32_bf16(a[mi], b[ni], acc[mi][ni], 0, 0, 0);
  }
}

// ---------- gemm1 body: hbW[m_local,:] = quick_gelu(xb[t01+m,:] @ W1[e1]^T + b1) ----------
__device__ __forceinline__ void gemm1_body(u16* As, u16* Bs,
                                           const u16* __restrict__ xb,
                                           const u16* __restrict__ w1b,
                                           const float* __restrict__ b1,
                                           u16* __restrict__ hbW,
                                           int e1, int t01, int m0, int n0,
                                           int lane, int wave, int wr, int wc){
  f32x4 acc[4][4] = {};
  const u16* Ab = xb  + (long)(t01 + m0) * D_DIM;
  const u16* Bb = w1b + ((long)e1 * H_DIM + n0) * D_DIM;
  for (int kt = 0; kt < 12; ++kt){
    stage_tile(Ab + kt*64, (int)D_DIM, As, wave, lane);
    stage_tile(Bb + kt*64, (int)D_DIM, Bs, wave, lane);
    __syncthreads();
    mma_step(As, Bs, lane, wr, wc, acc);
    __syncthreads();
  }
  const int ln = lane & 15;
  float bias[4];
#pragma unroll
  for (int ni = 0; ni < 4; ++ni) bias[ni] = b1[(long)e1*H_DIM + n0 + wc*64 + ni*16 + ln];
#pragma unroll
  for (int mi = 0; mi < 4; ++mi){
#pragma unroll
    for (int j = 0; j < 4; ++j){
      const int r = m0 + wr*64 + mi*16 + (lane>>4)*4 + j;   // half-local row
      u16* dst = hbW + (long)r * H_DIM + n0 + wc*64;
#pragma unroll
      for (int ni = 0; ni < 4; ++ni){
        const float v  = acc[mi][ni][j] + bias[ni];
        const float gl = v / (1.0f + __expf(-1.702f * v));  // quick_gelu
        dst[ni*16 + ln] = f2bf(gl);
      }
    }
  }
}

// ---------- gemm2 body: out[t02+m,:] (+)= probs*(hbR[m,:] @ W2[e2]^T + b2) ----------
__device__ __forceinline__ void gemm2_body(u16* As, u16* Bs,
                                           const u16* __restrict__ hbR,
                                           const u16* __restrict__ w2b,
                                           const float* __restrict__ b2,
                                           const float* __restrict__ probs,
                                           float* __restrict__ out,
                                           int e2, int t02, int m0, int n0,
                                           int lane, int wave, int wr, int wc){
  f32x4 acc[4][4] = {};
  const u16* Ab = hbR + (long)m0 * H_DIM;
  const u16* Bb = w2b + ((long)e2 * D_DIM + n0) * H_DIM;
  for (int kt = 0; kt < 48; ++kt){
    stage_tile(Ab + kt*64, (int)H_DIM, As, wave, lane);
    stage_tile(Bb + kt*64, (int)H_DIM, Bs, wave, lane);
    __syncthreads();
    mma_step(As, Bs, lane, wr, wc, acc);
    __syncthreads();
  }
  const int ln = lane & 15;
  float bias[4];
#pragma unroll
  for (int ni = 0; ni < 4; ++ni) bias[ni] = b2[(long)e2*D_DIM + n0 + wc*64 + ni*16 + ln];
#pragma unroll
  for (int mi = 0; mi < 4; ++mi){
#pragma unroll
    for (int j = 0; j < 4; ++j){
      const int gt = t02 + m0 + wr*64 + mi*16 + (lane>>4)*4 + j;
      if (gt < (int)T_TOK){
        const float p = probs[(long)gt*8 + e2];
        float* dst = out + (long)gt * D_DIM + n0 + wc*64;
#pragma unroll
        for (int ni = 0; ni < 4; ++ni){
          const float v = p * (acc[mi][ni][j] + bias[ni]);
          if (e2 == 0) dst[ni*16 + ln] = v;
          else         dst[ni*16 + ln] += v;
        }
      }
    }
  }
}

// ---------- paired dispatch: gemm2(e2, one token-half) + gemm1(e1, other half) ----------
__global__ __launch_bounds__(256) void k_pair(const u16* __restrict__ xb,
                                              const u16* __restrict__ w1b,
                                              const float* __restrict__ b1,
                                              const u16* __restrict__ w2b,
                                              const float* __restrict__ b2,
                                              const float* __restrict__ probs,
                                              float* __restrict__ out,
                                              const u16* __restrict__ hbR,
                                              u16* __restrict__ hbW,
                                              int e2, int t02, int mt2,
                                              int e1, int t01, int mt1, int n2){
  __shared__ alignas(16) u16 As[8192];
  __shared__ alignas(16) u16 Bs[8192];
  const int tid = threadIdx.x, lane = tid & 63, wave = tid >> 6;
  const int wr = wave >> 1, wc = wave & 1;
  const int bx = (int)blockIdx.x;
  if (bx < n2){
    // gemm2 sub-grid: XCD-chunked, y-fastest (A-panel reused by 6 consecutive blocks)
    const int wg = xcd_chunk(bx, n2);
    const int tx = wg / 6, ty = wg % 6;
    gemm2_body(As, Bs, hbR, w2b, b2, probs, out, e2, t02, tx << 7, ty << 7,
               lane, wave, wr, wc);
  } else {
    // gemm1 sub-grid: XCD-chunked, x-fastest (B-panel reused along the chunk)
    const int n1 = (int)gridDim.x - n2;
    const int wg = xcd_chunk(bx - n2, n1);
    const int tx = wg % mt1, ty = wg / mt1;
    gemm1_body(As, Bs, xb, w1b, b1, hbW, e1, t01, tx << 7, ty << 7,
               lane, wave, wr, wc);
  }
}

// ---------- host ----------
extern "C" void kernel_launch(void* const* d_in, const int* in_sizes, int n_in,
                              void* d_out, int out_size, void* d_ws, size_t ws_size,
                              hipStream_t stream){
  const float* x  = (const float*)d_in[0];
  const float* W1 = (const float*)d_in[1];
  const float* b1 = (const float*)d_in[2];
  const float* W2 = (const float*)d_in[3];
  const float* b2 = (const float*)d_in[4];
  const float* Wr = (const float*)d_in[5];
  const float* br = (const float*)d_in[6];
  float* out = (float*)d_out;

  char* ws = (char*)d_ws;
  size_t off = 0;
  auto carve = [&](size_t bytes)->void*{
    void* p = ws + off; off += (bytes + 255) & ~(size_t)255; return p;
  };
  u16*   xb    = (u16*)  carve((size_t)M_PAD * D_DIM * 2);
  u16*   w1b   = (u16*)  carve((size_t)E_NUM * H_DIM * D_DIM * 2);
  u16*   w2b   = (u16*)  carve((size_t)E_NUM * D_DIM * H_DIM * 2);
  float* probs = (float*)carve((size_t)T_TOK * E_NUM * 4);
  u16*   hbA   = (u16*)  carve((size_t)8192 * H_DIM * 2);   // tokens [0, 8192)
  u16*   hbB   = (u16*)  carve((size_t)8320 * H_DIM * 2);   // tokens [8192, 16512)

  // conversions + router
  k_conv<<<dim3(2048), dim3(256), 0, stream>>>(x,  xb,  T_TOK*D_DIM, M_PAD*D_DIM);
  k_conv<<<dim3(2048), dim3(256), 0, stream>>>(W1, w1b, E_NUM*H_DIM*D_DIM, E_NUM*H_DIM*D_DIM);
  k_conv<<<dim3(2048), dim3(256), 0, stream>>>(W2, w2b, E_NUM*D_DIM*H_DIM, E_NUM*D_DIM*H_DIM);
  k_router<<<dim3(4112), dim3(256), 0, stream>>>(x, Wr, br, probs);

  const int MTA = 64, MTB = 65;      // token-half tile counts
  const int T0A = 0,  T0B = 8192;

  auto pair = [&](int e2, const u16* hbR, int t02, int mt2,
                  int e1, u16* hbW, int t01, int mt1){
    const int n2 = mt2 * 6, n1 = mt1 * 24;
    k_pair<<<dim3((unsigned)(n2 + n1)), dim3(256), 0, stream>>>(
        xb, w1b, b1, w2b, b2, probs, out, hbR, hbW,
        e2, t02, mt2, e1, t01, mt1, n2);
  };

  // D0: g1(0,A)
  pair(0, nullptr, 0, 0, 0, hbA, T0A, MTA);
  for (int e = 0; e < 8; ++e){
    // g2(e,A) + g1(e,B)
    pair(e, hbA, T0A, MTA, e, hbB, T0B, MTB);
    // g2(e,B) + g1(e+1,A)
    if (e < 7) pair(e, hbB, T0B, MTB, e + 1, hbA, T0A, MTA);
  }
  // D16: g2(7,B)
  pair(7, hbB, T0B, MTB, 0, nullptr, 0, 0);
}

// Round 4
// 2119.489 us; speedup vs baseline: 1.7156x; 1.0549x over previous
//
#include <hip/hip_runtime.h>

typedef unsigned short u16;
typedef float f32x4 __attribute__((ext_vector_type(4)));
typedef short s16x8 __attribute__((ext_vector_type(8)));

#define T_TOK   16448L   // 257*64
#define D_DIM   768L
#define H_DIM   3072L
#define E_NUM   8L
#define M_PAD   16640L   // 65*256 ; halves: A=8192 rows (32 tiles), B=8448 rows (33 tiles)

// ---------- helpers ----------
__device__ __forceinline__ u16 f2bf(float f){
  unsigned u = __float_as_uint(f);
  u = u + 0x7FFFu + ((u >> 16) & 1u);          // RNE
  return (u16)(u >> 16);
}
__device__ __forceinline__ unsigned f2bf2(float a, float b){
  return (unsigned)f2bf(a) | ((unsigned)f2bf(b) << 16);
}

__device__ __forceinline__ void gload_lds16(const u16* g, u16* s){
  __builtin_amdgcn_global_load_lds((const __attribute__((address_space(1))) void*)g,
                                   (__attribute__((address_space(3))) void*)s,
                                   16, 0, 0);
}

// bijective XCD chunking (m204)
__device__ __forceinline__ int xcd_chunk(int idx, int n){
  const int q = n >> 3, r = n & 7, x = idx & 7;
  return (x < r ? x*(q+1) : r*(q+1) + (x-r)*q) + (idx >> 3);
}

// ---------- fp32 -> bf16 (zero-padded tail) ----------
__global__ void k_conv(const float* __restrict__ in, u16* __restrict__ outp,
                       long nValid, long nTotal){
  long i = (long)blockIdx.x * blockDim.x + threadIdx.x;
  long stride = (long)gridDim.x * blockDim.x;
  long n8 = nTotal >> 3;
  for (long v = i; v < n8; v += stride){
    long base = v << 3;
    uint4 o;
    if (base < nValid){
      const float4 f0 = *(const float4*)(in + base);
      const float4 f1 = *(const float4*)(in + base + 4);
      o.x = f2bf2(f0.x, f0.y); o.y = f2bf2(f0.z, f0.w);
      o.z = f2bf2(f1.x, f1.y); o.w = f2bf2(f1.z, f1.w);
    } else {
      o.x = 0u; o.y = 0u; o.z = 0u; o.w = 0u;
    }
    *(uint4*)(outp + base) = o;
  }
}

// ---------- router: logits + softmax (fp32, one wave per token) ----------
__global__ void k_router(const float* __restrict__ x, const float* __restrict__ Wr,
                         const float* __restrict__ br, float* __restrict__ probs){
  int w = (int)((blockIdx.x * (long)blockDim.x + threadIdx.x) >> 6);
  int lane = threadIdx.x & 63;
  if (w >= (int)T_TOK) return;
  const float* xr = x + (long)w * D_DIM;
  float l[8];
#pragma unroll
  for (int e = 0; e < 8; ++e) l[e] = 0.f;
#pragma unroll
  for (int c = 0; c < 3; ++c){
    const float4 xv = *(const float4*)(xr + c*256 + lane*4);
#pragma unroll
    for (int e = 0; e < 8; ++e){
      const float4 wv = *(const float4*)(Wr + (long)e*D_DIM + c*256 + lane*4);
      l[e] += xv.x*wv.x + xv.y*wv.y + xv.z*wv.z + xv.w*wv.w;
    }
  }
#pragma unroll
  for (int e = 0; e < 8; ++e){
#pragma unroll
    for (int off = 32; off > 0; off >>= 1) l[e] += __shfl_xor(l[e], off);
    l[e] += br[e];
  }
  float m = l[0];
#pragma unroll
  for (int e = 1; e < 8; ++e) m = fmaxf(m, l[e]);
  float s = 0.f;
#pragma unroll
  for (int e = 0; e < 8; ++e){ l[e] = __expf(l[e] - m); s += l[e]; }
  float inv = 1.f / s;
  if (lane == 0){
    float4 p0 = { l[0]*inv, l[1]*inv, l[2]*inv, l[3]*inv };
    float4 p1 = { l[4]*inv, l[5]*inv, l[6]*inv, l[7]*inv };
    *(float4*)(probs + (long)w*8)     = p0;
    *(float4*)(probs + (long)w*8 + 4) = p1;
  }
}

// ---------- 256x64 tile staging (8 waves, pre-swizzled source, linear LDS dest) ----------
// LDS[row][chunk p] holds source chunk p ^ (row&7); rows are 64 elems (128 B).
__device__ __forceinline__ void stage256(const u16* __restrict__ gbase, long ldk,
                                         u16* sbase, int l, int w){
  const int rw = l >> 3;                       // 0..7
  const int c8 = (l & 7) ^ rw;                 // swizzled source 16B-chunk
  const u16* g = gbase + (long)(w*8 + rw) * ldk + c8*8;
  u16* s = sbase + w*512;                      // wave-uniform base, lane-linear dest
#pragma unroll
  for (int i = 0; i < 4; ++i)
    gload_lds16(g + (long)(i*64) * ldk, s + i*4096);   // rows i*64 + w*8 + rw
}

// read one 16-row MFMA fragment: rows rbase..rbase+15, logical k-chunk c (0..7)
__device__ __forceinline__ s16x8 ld_frag(const u16* S, int rbase, int c, int ln){
  const int r = rbase + ln;
  return *(const s16x8*)(S + (r << 6) + ((c ^ (r & 7)) << 3));
}

// ---------- deep-pipelined 256x256 GEMM body (BK=64, counted vmcnt) ----------
__device__ __forceinline__ void gemm256(const u16* __restrict__ Ag, long lda,
                                        const u16* __restrict__ Bg, long ldb,
                                        int NT, u16* lds0, u16* lds1,
                                        int tid, f32x4 (&acc)[8][4]){
  const int l  = tid & 63, w = tid >> 6;
  const int wr = w >> 2,  wc = w & 3;
  const int g4 = l >> 4,  ln = l & 15;
  u16* cur = lds0; u16* nxt = lds1;

  // prologue: tiles 0 and 1 in flight; wait tile 0 (8 newest stay outstanding)
  stage256(Ag,       lda, cur,         l, w);
  stage256(Bg,       ldb, cur + 16384, l, w);
  stage256(Ag + 64,  lda, nxt,         l, w);
  stage256(Bg + 64,  ldb, nxt + 16384, l, w);
  asm volatile("s_waitcnt vmcnt(8)" ::: "memory");
  __builtin_amdgcn_sched_barrier(0);
  __builtin_amdgcn_s_barrier();
  __builtin_amdgcn_sched_barrier(0);

  for (int kt = 0; kt < NT; ++kt){
    const u16* As = cur;
    const u16* Bs = cur + 16384;
    s16x8 a[4], b[4];
    // ---- P0: k-half 0, A rows 0..63 of wave tile ----
#pragma unroll
    for (int ni = 0; ni < 4; ++ni) b[ni] = ld_frag(Bs, wc*64 + ni*16, g4, ln);
#pragma unroll
    for (int mi = 0; mi < 4; ++mi) a[mi] = ld_frag(As, wr*128 + mi*16, g4, ln);
    __builtin_amdgcn_s_setprio(1);
#pragma unroll
    for (int mi = 0; mi < 4; ++mi)
#pragma unroll
      for (int ni = 0; ni < 4; ++ni)
        acc[mi][ni] = __builtin_amdgcn_mfma_f32_16x16x32_bf16(a[mi], b[ni], acc[mi][ni], 0, 0, 0);
    __builtin_amdgcn_s_setprio(0);
    // ---- P1: k-half 0, A rows 64..127 ----
#pragma unroll
    for (int mi = 0; mi < 4; ++mi) a[mi] = ld_frag(As, wr*128 + (mi+4)*16, g4, ln);
    __builtin_amdgcn_s_setprio(1);
#pragma unroll
    for (int mi = 0; mi < 4; ++mi)
#pragma unroll
      for (int ni = 0; ni < 4; ++ni)
        acc[mi+4][ni] = __builtin_amdgcn_mfma_f32_16x16x32_bf16(a[mi], b[ni], acc[mi+4][ni], 0, 0, 0);
    __builtin_amdgcn_s_setprio(0);
    // ---- P2: k-half 1, A rows 0..63 ----
#pragma unroll
    for (int ni = 0; ni < 4; ++ni) b[ni] = ld_frag(Bs, wc*64 + ni*16, 4 + g4, ln);
#pragma unroll
    for (int mi = 0; mi < 4; ++mi) a[mi] = ld_frag(As, wr*128 + mi*16, 4 + g4, ln);
    __builtin_amdgcn_s_setprio(1);
#pragma unroll
    for (int mi = 0; mi < 4; ++mi)
#pragma unroll
      for (int ni = 0; ni < 4; ++ni)
        acc[mi][ni] = __builtin_amdgcn_mfma_f32_16x16x32_bf16(a[mi], b[ni], acc[mi][ni], 0, 0, 0);
    __builtin_amdgcn_s_setprio(0);
    // ---- P3: k-half 1, A rows 64..127 ----
#pragma unroll
    for (int mi = 0; mi < 4; ++mi) a[mi] = ld_frag(As, wr*128 + (mi+4)*16, 4 + g4, ln);
    __builtin_amdgcn_s_setprio(1);
#pragma unroll
    for (int mi = 0; mi < 4; ++mi)
#pragma unroll
      for (int ni = 0; ni < 4; ++ni)
        acc[mi+4][ni] = __builtin_amdgcn_mfma_f32_16x16x32_bf16(a[mi], b[ni], acc[mi+4][ni], 0, 0, 0);
    __builtin_amdgcn_s_setprio(0);

    // ---- boundary: B1 -> stage kt+2 into retired buffer -> counted vmcnt -> B2 ----
    __builtin_amdgcn_sched_barrier(0);
    __builtin_amdgcn_s_barrier();            // all waves done reading cur
    __builtin_amdgcn_sched_barrier(0);
    if (kt + 2 < NT){
      stage256(Ag + (long)(kt+2)*64, lda, cur,         l, w);
      stage256(Bg + (long)(kt+2)*64, ldb, cur + 16384, l, w);
      asm volatile("s_waitcnt vmcnt(8)" ::: "memory");   // kt+1 landed; kt+2 in flight
    } else {
      asm volatile("s_waitcnt vmcnt(0)" ::: "memory");   // tail: drain
    }
    __builtin_amdgcn_sched_barrier(0);
    __builtin_amdgcn_s_barrier();            // kt+1 visible to all
    __builtin_amdgcn_sched_barrier(0);
    u16* t = cur; cur = nxt; nxt = t;
  }
}

// ---------- paired dispatch: gemm2(e2, one token-half) + gemm1(e1, other half) ----------
__global__ __launch_bounds__(512, 2) void k_pair(const u16* __restrict__ xb,
                                                 const u16* __restrict__ w1b,
                                                 const float* __restrict__ b1,
                                                 const u16* __restrict__ w2b,
                                                 const float* __restrict__ b2,
                                                 const float* __restrict__ probs,
                                                 float* __restrict__ out,
                                                 const u16* __restrict__ hbR,
                                                 u16* __restrict__ hbW,
                                                 int e2, int t02,
                                                 int e1, int t01, int mt1, int n2){
  __shared__ alignas(16) u16 lds[2][32768];   // 128 KiB: [buf][A | B]
  const int tid = threadIdx.x;
  const int l  = tid & 63, w = tid >> 6;
  const int wr = w >> 2,  wc = w & 3;
  const int g4 = l >> 4,  ln = l & 15;
  const int bx = (int)blockIdx.x;
  f32x4 acc[8][4] = {};

  if (bx < n2){
    // ---- gemm2: XCD-chunked, y-fastest (3 N-tiles share the A-panel) ----
    const int wg = xcd_chunk(bx, n2);
    const int tx = wg / 3, ty = wg % 3;
    const int m0 = tx << 8, n0 = ty << 8;
    gemm256(hbR + (long)m0 * H_DIM, H_DIM,
            w2b + ((long)e2 * D_DIM + n0) * H_DIM, H_DIM,
            48, &lds[0][0], &lds[1][0], tid, acc);
    float bias[4];
#pragma unroll
    for (int ni = 0; ni < 4; ++ni) bias[ni] = b2[(long)e2*D_DIM + n0 + wc*64 + ni*16 + ln];
#pragma unroll
    for (int mi = 0; mi < 8; ++mi){
#pragma unroll
      for (int j = 0; j < 4; ++j){
        const int gt = t02 + m0 + wr*128 + mi*16 + g4*4 + j;
        if (gt < (int)T_TOK){
          const float p = probs[(long)gt*8 + e2];
          float* dst = out + (long)gt * D_DIM + n0 + wc*64;
#pragma unroll
          for (int ni = 0; ni < 4; ++ni){
            const float v = p * (acc[mi][ni][j] + bias[ni]);
            if (e2 == 0) dst[ni*16 + ln] = v;
            else         dst[ni*16 + ln] += v;
          }
        }
      }
    }
  } else {
    // ---- gemm1: XCD-chunked, x-fastest (B-panel reused along chunk) ----
    const int n1 = (int)gridDim.x - n2;
    const int wg = xcd_chunk(bx - n2, n1);
    const int tx = wg % mt1, ty = wg / mt1;
    const int m0 = tx << 8, n0 = ty << 8;
    gemm256(xb + (long)(t01 + m0) * D_DIM, D_DIM,
            w1b + ((long)e1 * H_DIM + n0) * D_DIM, D_DIM,
            12, &lds[0][0], &lds[1][0], tid, acc);
    float bias[4];
#pragma unroll
    for (int ni = 0; ni < 4; ++ni) bias[ni] = b1[(long)e1*H_DIM + n0 + wc*64 + ni*16 + ln];
#pragma unroll
    for (int mi = 0; mi < 8; ++mi){
#pragma unroll
      for (int j = 0; j < 4; ++j){
        const int r = m0 + wr*128 + mi*16 + g4*4 + j;     // half-local row
        u16* dst = hbW + (long)r * H_DIM + n0 + wc*64;
#pragma unroll
        for (int ni = 0; ni < 4; ++ni){
          const float v  = acc[mi][ni][j] + bias[ni];
          const float gl = v / (1.0f + __expf(-1.702f * v));  // quick_gelu
          dst[ni*16 + ln] = f2bf(gl);
        }
      }
    }
  }
}

// ---------- host ----------
extern "C" void kernel_launch(void* const* d_in, const int* in_sizes, int n_in,
                              void* d_out, int out_size, void* d_ws, size_t ws_size,
                              hipStream_t stream){
  const float* x  = (const float*)d_in[0];
  const float* W1 = (const float*)d_in[1];
  const float* b1 = (const float*)d_in[2];
  const float* W2 = (const float*)d_in[3];
  const float* b2 = (const float*)d_in[4];
  const float* Wr = (const float*)d_in[5];
  const float* br = (const float*)d_in[6];
  float* out = (float*)d_out;

  char* ws = (char*)d_ws;
  size_t off = 0;
  auto carve = [&](size_t bytes)->void*{
    void* p = ws + off; off += (bytes + 255) & ~(size_t)255; return p;
  };
  u16*   xb    = (u16*)  carve((size_t)M_PAD * D_DIM * 2);
  u16*   w1b   = (u16*)  carve((size_t)E_NUM * H_DIM * D_DIM * 2);
  u16*   w2b   = (u16*)  carve((size_t)E_NUM * D_DIM * H_DIM * 2);
  float* probs = (float*)carve((size_t)T_TOK * E_NUM * 4);
  u16*   hbA   = (u16*)  carve((size_t)8192 * H_DIM * 2);   // tokens [0, 8192)
  u16*   hbB   = (u16*)  carve((size_t)8448 * H_DIM * 2);   // tokens [8192, 16640)

  // conversions + router
  k_conv<<<dim3(2048), dim3(256), 0, stream>>>(x,  xb,  T_TOK*D_DIM, M_PAD*D_DIM);
  k_conv<<<dim3(2048), dim3(256), 0, stream>>>(W1, w1b, E_NUM*H_DIM*D_DIM, E_NUM*H_DIM*D_DIM);
  k_conv<<<dim3(2048), dim3(256), 0, stream>>>(W2, w2b, E_NUM*D_DIM*H_DIM, E_NUM*D_DIM*H_DIM);
  k_router<<<dim3(4112), dim3(256), 0, stream>>>(x, Wr, br, probs);

  const int MTA = 32, MTB = 33;      // 256-row tile counts per token-half
  const int T0A = 0,  T0B = 8192;

  auto pair = [&](int e2, const u16* hbR, int t02, int mt2,
                  int e1, u16* hbW, int t01, int mt1){
    const int n2 = mt2 * 3, n1 = mt1 * 12;
    k_pair<<<dim3((unsigned)(n2 + n1)), dim3(512), 0, stream>>>(
        xb, w1b, b1, w2b, b2, probs, out, hbR, hbW,
        e2, t02, e1, t01, mt1, n2);
  };

  // ping-pong: D0: g1(0,A); D(2e+1): g2(e,A)+g1(e,B); D(2e+2): g2(e,B)+g1(e+1,A); D16: g2(7,B)
  pair(0, nullptr, 0, 0, 0, hbA, T0A, MTA);
  for (int e = 0; e < 8; ++e){
    pair(e, hbA, T0A, MTA, e, hbB, T0B, MTB);
    if (e < 7) pair(e, hbB, T0B, MTB, e + 1, hbA, T0A, MTA);
  }
  pair(7, hbB, T0B, MTB, 0, nullptr, 0, 0);
}

// Round 6
// 2103.604 us; speedup vs baseline: 1.7285x; 1.0076x over previous
//
#include <hip/hip_runtime.h>

typedef unsigned short u16;
typedef float f32x4 __attribute__((ext_vector_type(4)));
typedef short s16x8 __attribute__((ext_vector_type(8)));

#define T_TOK   16448L   // 257*64
#define D_DIM   768L
#define H_DIM   3072L
#define E_NUM   8L
#define M_PAD   16640L   // 65*256 ; halves: A=8192 rows (32 tiles), B=8448 rows (33 tiles)

// ---------- helpers ----------
__device__ __forceinline__ u16 f2bf(float f){
  unsigned u = __float_as_uint(f);
  u = u + 0x7FFFu + ((u >> 16) & 1u);          // RNE
  return (u16)(u >> 16);
}
__device__ __forceinline__ unsigned f2bf2(float a, float b){
  return (unsigned)f2bf(a) | ((unsigned)f2bf(b) << 16);
}

__device__ __forceinline__ void gload_lds16(const u16* g, u16* s){
  __builtin_amdgcn_global_load_lds((const __attribute__((address_space(1))) void*)g,
                                   (__attribute__((address_space(3))) void*)s,
                                   16, 0, 0);
}

// bijective XCD chunking (m204)
__device__ __forceinline__ int xcd_chunk(int idx, int n){
  const int q = n >> 3, r = n & 7, x = idx & 7;
  return (x < r ? x*(q+1) : r*(q+1) + (x-r)*q) + (idx >> 3);
}

// ---------- fp32 -> bf16 (zero-padded tail) ----------
__global__ void k_conv(const float* __restrict__ in, u16* __restrict__ outp,
                       long nValid, long nTotal){
  long i = (long)blockIdx.x * blockDim.x + threadIdx.x;
  long stride = (long)gridDim.x * blockDim.x;
  long n8 = nTotal >> 3;
  for (long v = i; v < n8; v += stride){
    long base = v << 3;
    uint4 o;
    if (base < nValid){
      const float4 f0 = *(const float4*)(in + base);
      const float4 f1 = *(const float4*)(in + base + 4);
      o.x = f2bf2(f0.x, f0.y); o.y = f2bf2(f0.z, f0.w);
      o.z = f2bf2(f1.x, f1.y); o.w = f2bf2(f1.z, f1.w);
    } else {
      o.x = 0u; o.y = 0u; o.z = 0u; o.w = 0u;
    }
    *(uint4*)(outp + base) = o;
  }
}

// ---------- router: logits + softmax (fp32, one wave per token) ----------
__global__ void k_router(const float* __restrict__ x, const float* __restrict__ Wr,
                         const float* __restrict__ br, float* __restrict__ probs){
  int w = (int)((blockIdx.x * (long)blockDim.x + threadIdx.x) >> 6);
  int lane = threadIdx.x & 63;
  if (w >= (int)T_TOK) return;
  const float* xr = x + (long)w * D_DIM;
  float l[8];
#pragma unroll
  for (int e = 0; e < 8; ++e) l[e] = 0.f;
#pragma unroll
  for (int c = 0; c < 3; ++c){
    const float4 xv = *(const float4*)(xr + c*256 + lane*4);
#pragma unroll
    for (int e = 0; e < 8; ++e){
      const float4 wv = *(const float4*)(Wr + (long)e*D_DIM + c*256 + lane*4);
      l[e] += xv.x*wv.x + xv.y*wv.y + xv.z*wv.z + xv.w*wv.w;
    }
  }
#pragma unroll
  for (int e = 0; e < 8; ++e){
#pragma unroll
    for (int off = 32; off > 0; off >>= 1) l[e] += __shfl_xor(l[e], off);
    l[e] += br[e];
  }
  float m = l[0];
#pragma unroll
  for (int e = 1; e < 8; ++e) m = fmaxf(m, l[e]);
  float s = 0.f;
#pragma unroll
  for (int e = 0; e < 8; ++e){ l[e] = __expf(l[e] - m); s += l[e]; }
  float inv = 1.f / s;
  if (lane == 0){
    float4 p0 = { l[0]*inv, l[1]*inv, l[2]*inv, l[3]*inv };
    float4 p1 = { l[4]*inv, l[5]*inv, l[6]*inv, l[7]*inv };
    *(float4*)(probs + (long)w*8)     = p0;
    *(float4*)(probs + (long)w*8 + 4) = p1;
  }
}

// ---------- 256x64 tile staging (8 waves, pre-swizzled source, linear LDS dest) ----------
// LDS[r][p] = Gsrc[r][p ^ (r&7)] ; rows are 64 elems (128 B).
__device__ __forceinline__ void stage256(const u16* __restrict__ gbase, long ldk,
                                         u16* sbase, int l, int w){
  const int rw = l >> 3;                       // 0..7
  const int c8 = (l & 7) ^ rw;                 // swizzled source 16B-chunk
  const u16* g = gbase + (long)(w*8 + rw) * ldk + c8*8;
  u16* s = sbase + w*512;                      // wave-uniform base, lane-linear dest
#pragma unroll
  for (int i = 0; i < 4; ++i)
    gload_lds16(g + (long)(i*64) * ldk, s + i*4096);   // rows i*64 + w*8 + rw
}

// read one 16-row MFMA fragment: rows rbase..rbase+15, logical k-chunk c (0..7)
__device__ __forceinline__ s16x8 ld_frag(const u16* S, int rbase, int c, int ln){
  const int r = rbase + ln;
  return *(const s16x8*)(S + (r << 6) + ((c ^ (r & 7)) << 3));
}

#define FENCE()  __builtin_amdgcn_sched_barrier(0)
#define BAR()    do{ FENCE(); __builtin_amdgcn_s_barrier(); FENCE(); }while(0)

// ---------- 256x256 GEMM body: free-run K-tile body + counted-vmcnt boundary ----------
// LDS: 2 buffers x (A 32KB | B 32KB) = 128 KiB.
__device__ __forceinline__ void gemm256(const u16* __restrict__ Ag, long lda,
                                        const u16* __restrict__ Bg, long ldb,
                                        int NT, u16* lds0, u16* lds1,
                                        int tid, f32x4 (&acc)[8][4]){
  const int l  = tid & 63, w = tid >> 6;
  const int wr = w >> 2,  wc = w & 3;
  const int g4 = l >> 4,  ln = l & 15;
  u16* cur = lds0; u16* nxt = lds1;

  // prologue: tiles 0 and 1 in flight; wait tile 0 (8 newest stay outstanding)
  stage256(Ag,       lda, cur,         l, w);
  stage256(Bg,       ldb, cur + 16384, l, w);
  stage256(Ag + 64,  lda, nxt,         l, w);
  stage256(Bg + 64,  ldb, nxt + 16384, l, w);
  FENCE();
  asm volatile("s_waitcnt vmcnt(8)" ::: "memory");
  BAR();

  for (int kt = 0; kt < NT; ++kt){
    const u16* As = cur;
    const u16* Bs = cur + 16384;
    s16x8 a0[8], b0[4], a1[8], b1[4];

    // ---- one unbroken body per K-tile: 24 ds_read_b128 + 64 MFMA,
    //      compiler-scheduled (fine-grained lgkmcnt interleave) ----
#pragma unroll
    for (int ni = 0; ni < 4; ++ni) b0[ni] = ld_frag(Bs, wc*64 + ni*16, g4, ln);
#pragma unroll
    for (int mi = 0; mi < 8; ++mi) a0[mi] = ld_frag(As, wr*128 + mi*16, g4, ln);
#pragma unroll
    for (int mi = 0; mi < 8; ++mi)
#pragma unroll
      for (int ni = 0; ni < 4; ++ni)
        acc[mi][ni] = __builtin_amdgcn_mfma_f32_16x16x32_bf16(a0[mi], b0[ni], acc[mi][ni], 0, 0, 0);
#pragma unroll
    for (int ni = 0; ni < 4; ++ni) b1[ni] = ld_frag(Bs, wc*64 + ni*16, 4 + g4, ln);
#pragma unroll
    for (int mi = 0; mi < 8; ++mi) a1[mi] = ld_frag(As, wr*128 + mi*16, 4 + g4, ln);
#pragma unroll
    for (int mi = 0; mi < 8; ++mi)
#pragma unroll
      for (int ni = 0; ni < 4; ++ni)
        acc[mi][ni] = __builtin_amdgcn_mfma_f32_16x16x32_bf16(a1[mi], b1[ni], acc[mi][ni], 0, 0, 0);

    // ---- boundary: BAR1 (reads done) -> stage kt+2 into retired buffer
    //      -> counted vmcnt (never 0 in steady state) -> BAR2 ----
    BAR();
    if (kt + 2 < NT){
      stage256(Ag + (long)(kt+2)*64, lda, cur,         l, w);
      stage256(Bg + (long)(kt+2)*64, ldb, cur + 16384, l, w);
      FENCE();
      asm volatile("s_waitcnt vmcnt(8)" ::: "memory");   // kt+1 landed; kt+2 in flight
    } else {
      FENCE();
      asm volatile("s_waitcnt vmcnt(0)" ::: "memory");   // tail: drain
    }
    BAR();
    u16* t = cur; cur = nxt; nxt = t;
  }
}

// ---------- paired dispatch: gemm2(e2, one token-half) + gemm1(e1, other half) ----------
__global__ __launch_bounds__(512, 2) void k_pair(const u16* __restrict__ xb,
                                                 const u16* __restrict__ w1b,
                                                 const float* __restrict__ b1,
                                                 const u16* __restrict__ w2b,
                                                 const float* __restrict__ b2,
                                                 const float* __restrict__ probs,
                                                 float* __restrict__ out,
                                                 const u16* __restrict__ hbR,
                                                 u16* __restrict__ hbW,
                                                 int e2, int t02,
                                                 int e1, int t01, int mt1, int n2){
  __shared__ alignas(16) u16 lds[2][32768];   // 128 KiB: 2 bufs x (A 16384 | B 16384 elems)
  const int tid = threadIdx.x;
  const int l  = tid & 63, w = tid >> 6;
  const int wr = w >> 2,  wc = w & 3;
  const int g4 = l >> 4,  ln = l & 15;
  const int bx = (int)blockIdx.x;
  f32x4 acc[8][4] = {};

  if (bx < n2){
    // ---- gemm2: XCD-chunked, y-fastest (3 N-tiles share the A-panel) ----
    const int wg = xcd_chunk(bx, n2);
    const int tx = wg / 3, ty = wg % 3;
    const int m0 = tx << 8, n0 = ty << 8;
    gemm256(hbR + (long)m0 * H_DIM, H_DIM,
            w2b + ((long)e2 * D_DIM + n0) * H_DIM, H_DIM,
            48, &lds[0][0], &lds[1][0], tid, acc);
    float bias[4];
#pragma unroll
    for (int ni = 0; ni < 4; ++ni) bias[ni] = b2[(long)e2*D_DIM + n0 + wc*64 + ni*16 + ln];
#pragma unroll
    for (int mi = 0; mi < 8; ++mi){
#pragma unroll
      for (int j = 0; j < 4; ++j){
        const int gt = t02 + m0 + wr*128 + mi*16 + g4*4 + j;
        if (gt < (int)T_TOK){
          const float p = probs[(long)gt*8 + e2];
          float* dst = out + (long)gt * D_DIM + n0 + wc*64;
#pragma unroll
          for (int ni = 0; ni < 4; ++ni){
            const float v = p * (acc[mi][ni][j] + bias[ni]);
            if (e2 == 0) dst[ni*16 + ln] = v;
            else         dst[ni*16 + ln] += v;
          }
        }
      }
    }
  } else {
    // ---- gemm1: XCD-chunked, x-fastest (B-panel reused along chunk) ----
    const int n1 = (int)gridDim.x - n2;
    const int wg = xcd_chunk(bx - n2, n1);
    const int tx = wg % mt1, ty = wg / mt1;
    const int m0 = tx << 8, n0 = ty << 8;
    gemm256(xb + (long)(t01 + m0) * D_DIM, D_DIM,
            w1b + ((long)e1 * H_DIM + n0) * D_DIM, D_DIM,
            12, &lds[0][0], &lds[1][0], tid, acc);
    float bias[4];
#pragma unroll
    for (int ni = 0; ni < 4; ++ni) bias[ni] = b1[(long)e1*H_DIM + n0 + wc*64 + ni*16 + ln];
#pragma unroll
    for (int mi = 0; mi < 8; ++mi){
#pragma unroll
      for (int j = 0; j < 4; ++j){
        const int r = m0 + wr*128 + mi*16 + g4*4 + j;     // half-local row
        u16* dst = hbW + (long)r * H_DIM + n0 + wc*64;
#pragma unroll
        for (int ni = 0; ni < 4; ++ni){
          const float v  = acc[mi][ni][j] + bias[ni];
          const float gl = v / (1.0f + __expf(-1.702f * v));  // quick_gelu
          dst[ni*16 + ln] = f2bf(gl);
        }
      }
    }
  }
}

// ---------- host ----------
extern "C" void kernel_launch(void* const* d_in, const int* in_sizes, int n_in,
                              void* d_out, int out_size, void* d_ws, size_t ws_size,
                              hipStream_t stream){
  const float* x  = (const float*)d_in[0];
  const float* W1 = (const float*)d_in[1];
  const float* b1 = (const float*)d_in[2];
  const float* W2 = (const float*)d_in[3];
  const float* b2 = (const float*)d_in[4];
  const float* Wr = (const float*)d_in[5];
  const float* br = (const float*)d_in[6];
  float* out = (float*)d_out;

  char* ws = (char*)d_ws;
  size_t off = 0;
  auto carve = [&](size_t bytes)->void*{
    void* p = ws + off; off += (bytes + 255) & ~(size_t)255; return p;
  };
  u16*   xb    = (u16*)  carve((size_t)M_PAD * D_DIM * 2);
  u16*   w1b   = (u16*)  carve((size_t)E_NUM * H_DIM * D_DIM * 2);
  u16*   w2b   = (u16*)  carve((size_t)E_NUM * D_DIM * H_DIM * 2);
  float* probs = (float*)carve((size_t)T_TOK * E_NUM * 4);
  u16*   hbA   = (u16*)  carve((size_t)8192 * H_DIM * 2);   // tokens [0, 8192)
  u16*   hbB   = (u16*)  carve((size_t)8448 * H_DIM * 2);   // tokens [8192, 16640)

  // conversions + router
  k_conv<<<dim3(2048), dim3(256), 0, stream>>>(x,  xb,  T_TOK*D_DIM, M_PAD*D_DIM);
  k_conv<<<dim3(2048), dim3(256), 0, stream>>>(W1, w1b, E_NUM*H_DIM*D_DIM, E_NUM*H_DIM*D_DIM);
  k_conv<<<dim3(2048), dim3(256), 0, stream>>>(W2, w2b, E_NUM*D_DIM*H_DIM, E_NUM*D_DIM*H_DIM);
  k_router<<<dim3(4112), dim3(256), 0, stream>>>(x, Wr, br, probs);

  const int MTA = 32, MTB = 33;      // 256-row tile counts per token-half
  const int T0A = 0,  T0B = 8192;

  auto pair = [&](int e2, const u16* hbR, int t02, int mt2,
                  int e1, u16* hbW, int t01, int mt1){
    const int n2 = mt2 * 3, n1 = mt1 * 12;
    k_pair<<<dim3((unsigned)(n2 + n1)), dim3(512), 0, stream>>>(
        xb, w1b, b1, w2b, b2, probs, out, hbR, hbW,
        e2, t02, e1, t01, mt1, n2);
  };

  // ping-pong: D0: g1(0,A); D(2e+1): g2(e,A)+g1(e,B); D(2e+2): g2(e,B)+g1(e+1,A); D16: g2(7,B)
  pair(0, nullptr, 0, 0, 0, hbA, T0A, MTA);
  for (int e = 0; e < 8; ++e){
    pair(e, hbA, T0A, MTA, e, hbB, T0B, MTB);
    if (e < 7) pair(e, hbB, T0B, MTB, e + 1, hbA, T0A, MTA);
  }
  pair(7, hbB, T0B, MTB, 0, nullptr, 0, 0);
}